// Round 7
// baseline (671.664 us; speedup 1.0000x reference)
//
#include <hip/hip_runtime.h>

// Problem constants
#define B_   32
#define C_   256
#define HW_  1024
#define N_   32768      // B_*HW_
#define M_   2000
#define MP_  2048       // M padded (rows >= 2000 are zero)
#define K_   256

typedef __attribute__((ext_vector_type(8))) _Float16 f16x8;
typedef __attribute__((ext_vector_type(4))) float f32x4;

#define KCAP 32
#define AP   264        // Ahs/Als row stride in halfwords

#define MFMA16(a, b, c) __builtin_amdgcn_mfma_f32_16x16x32_f16(a, b, c, 0, 0, 0)

// ---------------- prep: mem*64 -> fp16 hi/lo, staged-GEMM layout -----------
// mhs layout: [kslice 8][m 2048][slot 8][hw 8] fp16 (128B per (kslice,m) row).
// slots 0-3 = hi halfwords kk=0..31, slots 4-7 = lo. Stored slot s' = s^(m&7)
// (XOR pre-swizzle; global_load_lds copies linearly -> LDS image swizzled,
// ds_read applies the same XOR => conflict-free; rule #21 both-sides).
// K itself is nibble-permuted (position p holds channel 16*(p&15)+(p>>4)),
// matching the fused kernel's x-transpose order.
__global__ void prep_memS_kernel(const float* __restrict__ mem,
                                 _Float16* __restrict__ mhs) {
  int m = blockIdx.x;           // 0..2047
  int p = threadIdx.x;          // 0..255 (permuted-k position)
  int c = ((p & 15) << 4) | (p >> 4);
  float v = (m < M_) ? mem[m * K_ + c] * 64.0f : 0.0f;
  _Float16 h = (_Float16)v;
  _Float16 l = (_Float16)(v - (float)h);
  int ks = p >> 5, kk = p & 31;
  int sh = (kk >> 3) ^ (m & 7);
  int sl = ((kk >> 3) + 4) ^ (m & 7);
  size_t base = ((size_t)ks * MP_ + m) * 64;    // 64 halfwords per row
  mhs[base + sh * 8 + (kk & 7)] = h;
  mhs[base + sl * 8 + (kk & 7)] = l;
}

// ---------------- fused: GEMM1 + softmax-threshold + att + sparse GEMM2 ----
// One WG = 32 pixel rows x ALL 2048 m; 8 waves, wave w owns m-rows
// ch*128 + w*16 + row16 per chunk ch (16 chunks of 128). B staged via
// double-buffered global_load_lds, 128 units (8 kslices x 16 chunks), one
// barrier per unit. LDS trimmed to ~74 KB (Bs 32 KB dbuf; xs ALIASES Ahs/Als
// via register-roundtrip transpose) -> 2 WGs/CU for cross-WG latency hiding.
__global__ __launch_bounds__(512, 4) void fused_kernel(
    const float* __restrict__ x, const _Float16* __restrict__ mhs,
    const float* __restrict__ mem,
    float* __restrict__ y, float* __restrict__ att) {
  __shared__ _Float16 Bs[2][128 * 64];          // 2 x 16 KB staged B blocks
  __shared__ __align__(16) char axbuf[33792];   // xs (256x33 f32) == Ah+Al
  __shared__ float S_part[8][32];
  __shared__ float Sthr[32];
  __shared__ float inv_s[32];
  __shared__ unsigned int kcnt[32];
  __shared__ unsigned int km[32][KCAP];
  __shared__ float kp[32][KCAP];

  float    (*xs)[33]  = (float    (*)[33])axbuf;
  _Float16 (*Ahs)[AP] = (_Float16 (*)[AP])axbuf;
  _Float16 (*Als)[AP] = (_Float16 (*)[AP])(axbuf + 16896);

  const int tid   = threadIdx.x;
  const int lane  = tid & 63;
  const int wave  = tid >> 6;        // 0..7
  const int row16 = lane & 15;
  const int quad  = lane >> 4;
  const int r7    = row16 & 7;
  const int n0  = blockIdx.x * 32;
  const int b   = n0 >> 10;
  const int hw0 = n0 & 1023;

  // ---- staging helper: one 16KB B unit (contiguous in global) ----
#define STAGE(bufidx, unit) do {                                              \
    const _Float16* gs_ = mhs + (size_t)(unit) * 8192;                        \
    _Float16* ld_ = &Bs[bufidx][0];                                           \
    __builtin_amdgcn_global_load_lds(                                         \
      (const __attribute__((address_space(1))) unsigned int*)(gs_ + tid * 8), \
      (__attribute__((address_space(3))) unsigned int*)(ld_ + tid * 8),       \
      16, 0, 0);                                                              \
    __builtin_amdgcn_global_load_lds(                                         \
      (const __attribute__((address_space(1))) unsigned int*)(gs_ + (512 + tid) * 8), \
      (__attribute__((address_space(3))) unsigned int*)(ld_ + (512 + tid) * 8),       \
      16, 0, 0);                                                              \
  } while (0)

  // prologue: stage unit 0 immediately (completes in shadow of phases 0-1)
  STAGE(0, 0);

  // ---- phase 0: stage x[b][*][hw0..hw0+31] -> xs (coalesced) ----
  {
    const int c = tid >> 1;
    const int h16 = (tid & 1) * 16;
    const float* src = x + ((size_t)b * C_ + c) * HW_ + hw0 + h16;
#pragma unroll
    for (int i = 0; i < 4; ++i)
      *(f32x4*)(&xs[c][h16 + i * 4]) = *(const f32x4*)(src + i * 4);
  }
  if (tid < 32) kcnt[tid] = 0;
  __syncthreads();

  // ---- phase 1: transpose-convert xs -> Ahs/Als via REGISTER ROUNDTRIP ----
  // (xs and Ahs/Als alias; read all 16 values into VGPRs, barrier, write.)
  {
    const int nl = tid >> 4;             // 0..31
    const int g  = tid & 15;
    float v[16];
#pragma unroll
    for (int u = 0; u < 16; ++u) v[u] = xs[u * 16 + g][nl];
    __syncthreads();                     // all reads done before overwrite
    f16x8 hi0, hi1, lo0, lo1;
#pragma unroll
    for (int u = 0; u < 8; ++u) {
      _Float16 h = (_Float16)v[u];
      hi0[u] = h; lo0[u] = (_Float16)(v[u] - (float)h);
    }
#pragma unroll
    for (int u = 0; u < 8; ++u) {
      _Float16 h = (_Float16)v[u + 8];
      hi1[u] = h; lo1[u] = (_Float16)(v[u + 8] - (float)h);
    }
    *(f16x8*)(&Ahs[nl][g * 16])     = hi0;
    *(f16x8*)(&Ahs[nl][g * 16 + 8]) = hi1;
    *(f16x8*)(&Als[nl][g * 16])     = lo0;
    *(f16x8*)(&Als[nl][g * 16 + 8]) = lo1;
  }
  __syncthreads();

  // ---- phase 2: GEMM, 128 units, dbuf pipeline ----
  f32x4 acc[16][2];
#pragma unroll
  for (int ch = 0; ch < 16; ++ch)
#pragma unroll
    for (int nf = 0; nf < 2; ++nf) acc[ch][nf] = (f32x4){0.f, 0.f, 0.f, 0.f};

  const int mA = wave * 16;            // wave's m base within each 128-chunk
  const int sH = (quad ^ r7) * 8;      // swizzled hi slot (halfword offset)
  const int sL = ((4 | quad) ^ r7) * 8;

#pragma unroll 1
  for (int ks = 0; ks < 8; ++ks) {
    f16x8 ah[2], al[2];
#pragma unroll
    for (int nf = 0; nf < 2; ++nf) {
      ah[nf] = *(const f16x8*)(&Ahs[nf * 16 + row16][ks * 32 + quad * 8]);
      al[nf] = *(const f16x8*)(&Als[nf * 16 + row16][ks * 32 + quad * 8]);
    }
#pragma unroll
    for (int ch = 0; ch < 16; ++ch) {
      const int u = ks * 16 + ch;
      if (u < 127) STAGE((u + 1) & 1, u + 1);
      const _Float16* bp = &Bs[u & 1][(mA + row16) * 64];
      f16x8 bh = *(const f16x8*)(bp + sH);
      f16x8 bl = *(const f16x8*)(bp + sL);
      acc[ch][0] = MFMA16(ah[0], bh, acc[ch][0]);
      acc[ch][1] = MFMA16(ah[1], bh, acc[ch][1]);
      acc[ch][0] = MFMA16(al[0], bh, acc[ch][0]);
      acc[ch][1] = MFMA16(al[1], bh, acc[ch][1]);
      acc[ch][0] = MFMA16(ah[0], bl, acc[ch][0]);
      acc[ch][1] = MFMA16(ah[1], bl, acc[ch][1]);
      __syncthreads();
    }
  }

  // ---- phase 3: exp in place (mask padded m), then S rowsums ----
#pragma unroll
  for (int ch = 0; ch < 16; ++ch) {
    const bool valid = (ch * 128 + mA) < M_;   // wave-uniform, 16-aligned
#pragma unroll
    for (int nf = 0; nf < 2; ++nf)
#pragma unroll
      for (int r = 0; r < 4; ++r)
        acc[ch][nf][r] = valid ? __expf(acc[ch][nf][r] * 0.015625f) : 0.f;
  }

  const int nlb = quad * 4;   // row r of frag nf -> n_local = nf*16 + nlb + r
#pragma unroll
  for (int nf = 0; nf < 2; ++nf)
#pragma unroll
    for (int r = 0; r < 4; ++r) {
      float s = 0.f;
#pragma unroll
      for (int ch = 0; ch < 16; ++ch) s += acc[ch][nf][r];
      s += __shfl_xor(s, 1, 16);
      s += __shfl_xor(s, 2, 16);
      s += __shfl_xor(s, 4, 16);
      s += __shfl_xor(s, 8, 16);
      if (row16 == 0) S_part[wave][nf * 16 + nlb + r] = s;
    }
  __syncthreads();
  if (tid < 32) {
    float s = 0.f;
#pragma unroll
    for (int w = 0; w < 8; ++w) s += S_part[w][tid];
    Sthr[tid] = 0.0025f * s;
  }
  __syncthreads();

  // ---- phase 4: keep-scan (S2 + per-row lists) ----
#pragma unroll
  for (int nf = 0; nf < 2; ++nf)
#pragma unroll
    for (int r = 0; r < 4; ++r) {
      const int nl = nf * 16 + nlb + r;
      const float thr = Sthr[nl];
      float s2 = 0.f;
#pragma unroll
      for (int ch = 0; ch < 16; ++ch) {
        const float e = acc[ch][nf][r];
        if (e > thr) {
          s2 += e;
          unsigned int pos = atomicAdd(&kcnt[nl], 1u);
          if (pos < (unsigned)KCAP) {
            km[nl][pos] = (unsigned)(ch * 128 + mA + row16);
            kp[nl][pos] = e;
          }
        }
      }
      s2 += __shfl_xor(s2, 1, 16);
      s2 += __shfl_xor(s2, 2, 16);
      s2 += __shfl_xor(s2, 4, 16);
      s2 += __shfl_xor(s2, 8, 16);
      if (row16 == 0) S_part[wave][nl] = s2;
    }
  __syncthreads();
  if (tid < 32) {
    float s2 = 0.f;
#pragma unroll
    for (int w = 0; w < 8; ++w) s2 += S_part[w][tid];
    inv_s[tid] = (s2 > 0.f) ? 1.0f / s2 : 0.f;
  }
  __syncthreads();

  // ---- phase 5: att store direct from acc, threshold+scale fused inline ----
  {
    f32x4 thr4[2], iv4[2];
#pragma unroll
    for (int nf = 0; nf < 2; ++nf)
#pragma unroll
      for (int r = 0; r < 4; ++r) {
        thr4[nf][r] = Sthr[nf * 16 + nlb + r];
        iv4[nf][r]  = inv_s[nf * 16 + nlb + r];
      }
    float* attb = att + (size_t)b * M_ * HW_ + hw0;
#pragma unroll
    for (int ch = 0; ch < 16; ++ch) {
      if (ch * 128 + mA < M_) {          // wave-uniform
        const int m = ch * 128 + mA + row16;
        float* ar = attb + (size_t)m * HW_ + nlb;
        f32x4 p0, p1;
#pragma unroll
        for (int r = 0; r < 4; ++r) {
          const float e0 = acc[ch][0][r];
          const float e1 = acc[ch][1][r];
          p0[r] = (e0 > thr4[0][r]) ? e0 * iv4[0][r] : 0.f;
          p1[r] = (e1 > thr4[1][r]) ? e1 * iv4[1][r] : 0.f;
        }
        *(f32x4*)(ar)      = p0;
        *(f32x4*)(ar + 16) = p1;
      }
    }
  }

  // ---- phase 6: y sparse GEMM2, k-outer / ci-inner (16-deep MLP) ----
  {
    const int hwL = tid & 31;
    const int cq  = tid >> 5;              // 0..15
    unsigned int kc = kcnt[hwL];
    if (kc > (unsigned)KCAP) kc = KCAP;
    const float iv = inv_s[hwL];
    float yv[16];
#pragma unroll
    for (int ci = 0; ci < 16; ++ci) yv[ci] = 0.f;
#pragma unroll 1
    for (unsigned int k = 0; k < kc; ++k) {
      const float p = kp[hwL][k];
      const float* mrow = mem + (size_t)km[hwL][k] * K_ + cq;
#pragma unroll
      for (int ci = 0; ci < 16; ++ci)
        yv[ci] += p * mrow[ci * 16];
    }
    float* yb = y + (size_t)b * C_ * HW_ + hw0 + hwL;
#pragma unroll
    for (int ci = 0; ci < 16; ++ci)
      yb[(size_t)(ci * 16 + cq) * HW_] = yv[ci] * iv;
  }
#undef STAGE
}

// ---------------- host ----------------
extern "C" void kernel_launch(void* const* d_in, const int* in_sizes, int n_in,
                              void* d_out, int out_size, void* d_ws, size_t ws_size,
                              hipStream_t stream) {
  const float* x   = (const float*)d_in[0];      // [32,256,32,32]
  const float* mem = (const float*)d_in[1];      // [2000,256]
  float* y       = (float*)d_out;                              // 8388608 floats
  float* att_out = (float*)d_out + (size_t)B_ * C_ * HW_;      // 65536000 floats

  _Float16* mhs = (_Float16*)d_ws;               // 2 MB staged-B layout

  prep_memS_kernel<<<dim3(MP_), dim3(K_), 0, stream>>>(mem, mhs);
  fused_kernel<<<dim3(N_ / 32), dim3(512), 0, stream>>>(
      x, mhs, mem, y, att_out);
}

// Round 8
// 531.472 us; speedup vs baseline: 1.2638x; 1.2638x over previous
//
#include <hip/hip_runtime.h>

// Problem constants
#define B_   32
#define C_   256
#define HW_  1024
#define N_   32768      // B_*HW_
#define M_   2000
#define MP_  2048       // M padded (rows >= 2000 are zero)
#define K_   256

typedef __attribute__((ext_vector_type(8))) _Float16 f16x8;
typedef __attribute__((ext_vector_type(4))) float f32x4;

#define KCAP 32
#define AP   264        // Ahs/Als row stride in halfwords

#define MFMA16(a, b, c) __builtin_amdgcn_mfma_f32_16x16x32_f16(a, b, c, 0, 0, 0)

// ---------------- prep: mem*64 -> fp16 hi/lo, staged-GEMM layout -----------
// mhs layout: [kslice 8][m 2048][slot 8][hw 8] fp16 (128B per (kslice,m) row).
// slots 0-3 = hi halfwords kk=0..31, slots 4-7 = lo. Stored slot s' = s^(m&7)
// (XOR pre-swizzle; global_load_lds copies linearly -> LDS image swizzled,
// ds_read applies the same XOR => conflict-free; rule #21 both-sides).
// K itself is nibble-permuted (position p holds channel 16*(p&15)+(p>>4)),
// matching the fused kernel's x-transpose order.
__global__ void prep_memS_kernel(const float* __restrict__ mem,
                                 _Float16* __restrict__ mhs) {
  int m = blockIdx.x;           // 0..2047
  int p = threadIdx.x;          // 0..255 (permuted-k position)
  int c = ((p & 15) << 4) | (p >> 4);
  float v = (m < M_) ? mem[m * K_ + c] * 64.0f : 0.0f;
  _Float16 h = (_Float16)v;
  _Float16 l = (_Float16)(v - (float)h);
  int ks = p >> 5, kk = p & 31;
  int sh = (kk >> 3) ^ (m & 7);
  int sl = ((kk >> 3) + 4) ^ (m & 7);
  size_t base = ((size_t)ks * MP_ + m) * 64;    // 64 halfwords per row
  mhs[base + sh * 8 + (kk & 7)] = h;
  mhs[base + sl * 8 + (kk & 7)] = l;
}

// ---------------- fused: GEMM1 + softmax-threshold + att + sparse GEMM2 ----
// One WG = 32 pixel rows x ALL 2048 m (R6 structure: 8 waves, wave w owns
// m = ch*256 + w*32 + {0,16} + row16 per chunk). 64 staging units of 32 KB,
// double-buffered. R8 change: COUNTED-vmcnt pipeline (T3/T4) -- raw
// s_barrier + "s_waitcnt vmcnt(4)" instead of __syncthreads' vmcnt(0) drain,
// so the next unit's 4 loads stay in flight across the barrier; s_setprio
// around the MFMA cluster (T5). 1 WG/CU (216 regs/thread is the hard cap --
// R7's occupancy push just spilled).
__global__ __launch_bounds__(512, 1) void fused_kernel(
    const float* __restrict__ x, const _Float16* __restrict__ mhs,
    const float* __restrict__ mem,
    float* __restrict__ y, float* __restrict__ att) {
  __shared__ _Float16 Bs[2][256 * 64];    // 2 x 32 KB staged B blocks
  __shared__ float xs[256][33];           // 33.8 KB x-tile (separate: unit-0
                                          // staging overlaps phases 0-1)
  __shared__ _Float16 Ahs[32][AP];        // q hi (n-major, permuted-K rows)
  __shared__ _Float16 Als[32][AP];        // q lo
  __shared__ float S_part[8][32];
  __shared__ float Sthr[32];
  __shared__ float inv_s[32];
  __shared__ unsigned int kcnt[32];
  __shared__ unsigned int km[32][KCAP];
  __shared__ float kp[32][KCAP];

  const int tid   = threadIdx.x;
  const int lane  = tid & 63;
  const int wave  = tid >> 6;        // 0..7
  const int row16 = lane & 15;
  const int quad  = lane >> 4;
  const int r7    = row16 & 7;
  const int n0  = blockIdx.x * 32;
  const int b   = n0 >> 10;
  const int hw0 = n0 & 1023;

  // ---- staging helper: one 32KB B unit (contiguous in global) ----
#define STAGE(bufidx, unit) do {                                              \
    const _Float16* gs_ = mhs + (size_t)(unit) * 16384;                       \
    _Float16* ld_ = &Bs[bufidx][0];                                           \
    _Pragma("unroll")                                                         \
    for (int i_ = 0; i_ < 4; ++i_) {                                          \
      __builtin_amdgcn_global_load_lds(                                       \
        (const __attribute__((address_space(1))) unsigned int*)(gs_ + (i_ * 512 + tid) * 8), \
        (__attribute__((address_space(3))) unsigned int*)(ld_ + (i_ * 512 + tid) * 8),       \
        16, 0, 0);                                                            \
    }                                                                         \
  } while (0)

  // prologue: stage unit 0 NOW; it lands in the shadow of phases 0-1
  STAGE(0, 0);

  // ---- phase 0: stage x[b][*][hw0..hw0+31] -> xs (coalesced) ----
  {
    const int c = tid >> 1;
    const int h16 = (tid & 1) * 16;
    const float* src = x + ((size_t)b * C_ + c) * HW_ + hw0 + h16;
#pragma unroll
    for (int i = 0; i < 4; ++i)
      *(f32x4*)(&xs[c][h16 + i * 4]) = *(const f32x4*)(src + i * 4);
  }
  if (tid < 32) kcnt[tid] = 0;
  __syncthreads();

  // ---- phase 1: transpose-convert xs -> Ahs/Als (fp16 hi/lo, permuted K) --
  {
    const int nl = tid >> 4;             // 0..31
    const int g  = tid & 15;
    f16x8 hi0, hi1, lo0, lo1;
#pragma unroll
    for (int u = 0; u < 8; ++u) {
      float v = xs[u * 16 + g][nl];
      _Float16 h = (_Float16)v;
      hi0[u] = h; lo0[u] = (_Float16)(v - (float)h);
    }
#pragma unroll
    for (int u = 0; u < 8; ++u) {
      float v = xs[(u + 8) * 16 + g][nl];
      _Float16 h = (_Float16)v;
      hi1[u] = h; lo1[u] = (_Float16)(v - (float)h);
    }
    *(f16x8*)(&Ahs[nl][g * 16])     = hi0;
    *(f16x8*)(&Ahs[nl][g * 16 + 8]) = hi1;
    *(f16x8*)(&Als[nl][g * 16])     = lo0;
    *(f16x8*)(&Als[nl][g * 16 + 8]) = lo1;
  }
  __syncthreads();   // drains vmcnt too -> unit 0 guaranteed landed

  // ---- phase 2: GEMM, 64 units, counted-vmcnt dbuf pipeline ----
  f32x4 acc[8][2][2];
#pragma unroll
  for (int ch = 0; ch < 8; ++ch)
#pragma unroll
    for (int nf = 0; nf < 2; ++nf)
#pragma unroll
      for (int mf = 0; mf < 2; ++mf) acc[ch][nf][mf] = (f32x4){0.f, 0.f, 0.f, 0.f};

  const int mA = wave * 32;            // wave's m base within each chunk
  const int sH = (quad ^ r7) * 8;      // swizzled hi slot (halfword offset)
  const int sL = ((4 | quad) ^ r7) * 8;

#pragma unroll 1
  for (int ks = 0; ks < 8; ++ks) {
    f16x8 ah[2], al[2];
#pragma unroll
    for (int nf = 0; nf < 2; ++nf) {
      ah[nf] = *(const f16x8*)(&Ahs[nf * 16 + row16][ks * 32 + quad * 8]);
      al[nf] = *(const f16x8*)(&Als[nf * 16 + row16][ks * 32 + quad * 8]);
    }
#pragma unroll
    for (int ch = 0; ch < 8; ++ch) {
      const int u = ks * 8 + ch;
      // issue next unit's loads (other buffer; its readers all passed the
      // closing barrier of iter u-1)
      if (u < 63) {
        STAGE((u + 1) & 1, u + 1);
        // wait for unit u's 4 loads only; u+1's stay in flight (T4)
        asm volatile("s_waitcnt vmcnt(4)" ::: "memory");
      } else {
        asm volatile("s_waitcnt vmcnt(0)" ::: "memory");
      }
      __builtin_amdgcn_s_barrier();        // buf[u&1] ready for all waves
      __builtin_amdgcn_s_setprio(1);
      const _Float16* bp0 = &Bs[u & 1][(mA + row16) * 64];
      f16x8 bh0 = *(const f16x8*)(bp0 + sH);
      f16x8 bl0 = *(const f16x8*)(bp0 + sL);
      f16x8 bh1 = *(const f16x8*)(bp0 + 16 * 64 + sH);
      f16x8 bl1 = *(const f16x8*)(bp0 + 16 * 64 + sL);
      acc[ch][0][0] = MFMA16(ah[0], bh0, acc[ch][0][0]);
      acc[ch][1][0] = MFMA16(ah[1], bh0, acc[ch][1][0]);
      acc[ch][0][1] = MFMA16(ah[0], bh1, acc[ch][0][1]);
      acc[ch][1][1] = MFMA16(ah[1], bh1, acc[ch][1][1]);
      acc[ch][0][0] = MFMA16(al[0], bh0, acc[ch][0][0]);
      acc[ch][1][0] = MFMA16(al[1], bh0, acc[ch][1][0]);
      acc[ch][0][1] = MFMA16(al[0], bh1, acc[ch][0][1]);
      acc[ch][1][1] = MFMA16(al[1], bh1, acc[ch][1][1]);
      acc[ch][0][0] = MFMA16(ah[0], bl0, acc[ch][0][0]);
      acc[ch][1][0] = MFMA16(ah[1], bl0, acc[ch][1][0]);
      acc[ch][0][1] = MFMA16(ah[0], bl1, acc[ch][0][1]);
      acc[ch][1][1] = MFMA16(ah[1], bl1, acc[ch][1][1]);
      __builtin_amdgcn_s_setprio(0);
      __builtin_amdgcn_s_barrier();        // all reads of buf[u&1] done
    }
  }

  // ---- phase 3: exp in place (mask padded m), then S rowsums ----
#pragma unroll
  for (int ch = 0; ch < 8; ++ch)
#pragma unroll
    for (int mf = 0; mf < 2; ++mf) {
      const bool valid = (ch * 256 + mA + mf * 16) < M_;   // wave-uniform
#pragma unroll
      for (int nf = 0; nf < 2; ++nf)
#pragma unroll
        for (int r = 0; r < 4; ++r)
          acc[ch][nf][mf][r] = valid ? __expf(acc[ch][nf][mf][r] * 0.015625f) : 0.f;
    }

  const int nlb = quad * 4;   // row r of frag nf -> n_local = nf*16 + nlb + r
#pragma unroll
  for (int nf = 0; nf < 2; ++nf)
#pragma unroll
    for (int r = 0; r < 4; ++r) {
      float s = 0.f;
#pragma unroll
      for (int ch = 0; ch < 8; ++ch)
        s += acc[ch][nf][0][r] + acc[ch][nf][1][r];
      s += __shfl_xor(s, 1, 16);
      s += __shfl_xor(s, 2, 16);
      s += __shfl_xor(s, 4, 16);
      s += __shfl_xor(s, 8, 16);
      if (row16 == 0) S_part[wave][nf * 16 + nlb + r] = s;
    }
  __syncthreads();
  if (tid < 32) {
    float s = 0.f;
#pragma unroll
    for (int w = 0; w < 8; ++w) s += S_part[w][tid];
    Sthr[tid] = 0.0025f * s;
  }
  __syncthreads();

  // ---- phase 4: keep-scan (S2 + per-row lists) ----
#pragma unroll
  for (int nf = 0; nf < 2; ++nf)
#pragma unroll
    for (int r = 0; r < 4; ++r) {
      const int nl = nf * 16 + nlb + r;
      const float thr = Sthr[nl];
      float s2 = 0.f;
#pragma unroll
      for (int ch = 0; ch < 8; ++ch)
#pragma unroll
        for (int mf = 0; mf < 2; ++mf) {
          const float e = acc[ch][nf][mf][r];
          if (e > thr) {
            s2 += e;
            unsigned int pos = atomicAdd(&kcnt[nl], 1u);
            if (pos < (unsigned)KCAP) {
              km[nl][pos] = (unsigned)(ch * 256 + mA + mf * 16 + row16);
              kp[nl][pos] = e;
            }
          }
        }
      s2 += __shfl_xor(s2, 1, 16);
      s2 += __shfl_xor(s2, 2, 16);
      s2 += __shfl_xor(s2, 4, 16);
      s2 += __shfl_xor(s2, 8, 16);
      if (row16 == 0) S_part[wave][nl] = s2;
    }
  __syncthreads();
  if (tid < 32) {
    float s2 = 0.f;
#pragma unroll
    for (int w = 0; w < 8; ++w) s2 += S_part[w][tid];
    inv_s[tid] = (s2 > 0.f) ? 1.0f / s2 : 0.f;
  }
  __syncthreads();

  // ---- phase 5: att store direct from acc, threshold+scale fused inline ----
  {
    f32x4 thr4[2], iv4[2];
#pragma unroll
    for (int nf = 0; nf < 2; ++nf)
#pragma unroll
      for (int r = 0; r < 4; ++r) {
        thr4[nf][r] = Sthr[nf * 16 + nlb + r];
        iv4[nf][r]  = inv_s[nf * 16 + nlb + r];
      }
    float* attb = att + (size_t)b * M_ * HW_ + hw0;
#pragma unroll
    for (int ch = 0; ch < 8; ++ch)
#pragma unroll
      for (int mf = 0; mf < 2; ++mf) {
        if (ch * 256 + mA + mf * 16 < M_) {   // wave-uniform
          const int m = ch * 256 + mA + mf * 16 + row16;
          float* ar = attb + (size_t)m * HW_ + nlb;
          f32x4 p0, p1;
#pragma unroll
          for (int r = 0; r < 4; ++r) {
            const float e0 = acc[ch][0][mf][r];
            const float e1 = acc[ch][1][mf][r];
            p0[r] = (e0 > thr4[0][r]) ? e0 * iv4[0][r] : 0.f;
            p1[r] = (e1 > thr4[1][r]) ? e1 * iv4[1][r] : 0.f;
          }
          *(f32x4*)(ar)      = p0;
          *(f32x4*)(ar + 16) = p1;
        }
      }
  }

  // ---- phase 6: y sparse GEMM2, k-outer / ci-inner (16-deep MLP) ----
  {
    const int hwL = tid & 31;
    const int cq  = tid >> 5;              // 0..15
    unsigned int kc = kcnt[hwL];
    if (kc > (unsigned)KCAP) kc = KCAP;
    const float iv = inv_s[hwL];
    float yv[16];
#pragma unroll
    for (int ci = 0; ci < 16; ++ci) yv[ci] = 0.f;
#pragma unroll 1
    for (unsigned int k = 0; k < kc; ++k) {
      const float p = kp[hwL][k];
      const float* mrow = mem + (size_t)km[hwL][k] * K_ + cq;
#pragma unroll
      for (int ci = 0; ci < 16; ++ci)
        yv[ci] += p * mrow[ci * 16];
    }
    float* yb = y + (size_t)b * C_ * HW_ + hw0 + hwL;
#pragma unroll
    for (int ci = 0; ci < 16; ++ci)
      yb[(size_t)(ci * 16 + cq) * HW_] = yv[ci] * iv;
  }
#undef STAGE
}

// ---------------- host ----------------
extern "C" void kernel_launch(void* const* d_in, const int* in_sizes, int n_in,
                              void* d_out, int out_size, void* d_ws, size_t ws_size,
                              hipStream_t stream) {
  const float* x   = (const float*)d_in[0];      // [32,256,32,32]
  const float* mem = (const float*)d_in[1];      // [2000,256]
  float* y       = (float*)d_out;                              // 8388608 floats
  float* att_out = (float*)d_out + (size_t)B_ * C_ * HW_;      // 65536000 floats

  _Float16* mhs = (_Float16*)d_ws;               // 2 MB staged-B layout

  prep_memS_kernel<<<dim3(MP_), dim3(K_), 0, stream>>>(mem, mhs);
  fused_kernel<<<dim3(N_ / 32), dim3(512), 0, stream>>>(
      x, mhs, mem, y, att_out);
}